// Round 11
// baseline (215.451 us; speedup 1.0000x reference)
//
#include <hip/hip_runtime.h>
#include <hip/hip_bf16.h>

#define BB 4096
#define SZ 32
#define DD 10000
#define DPAD 10240
#define NMOD 64
#define NROWS_B 192   // cluster(64) + Mh(64) + Ml(64)
#define KSPLIT 4
#define KSEG 2560     // DPAD / KSPLIT

typedef __attribute__((ext_vector_type(4))) float f32x4;
typedef __attribute__((ext_vector_type(8))) short short8;

struct alignas(16) us8 { ushort v[8]; };

static __device__ __forceinline__ ushort f2bf(float f) {
    unsigned u = __builtin_bit_cast(unsigned, f);
    unsigned r = (u + 0x7fffu + ((u >> 16) & 1u)) >> 16;   // RNE
    return (ushort)r;
}

// sign pipeline: 1 iff cosf(t+bk)*sinf(t) > 0, else 0 (covers ==0 -> -1).
static __device__ __forceinline__ int sign_pm(float t, float bk) {
    if (t == 0.0f) return 0;                 // sin(+-0)=+-0 -> sample==+-0 -> -1
    const double INV_PI_D = 0.31830988618379067153776752674503;
    float v = t + bk;
    long long n1 = (long long)floor((double)t * INV_PI_D);
    long long n2 = (long long)floor(fma((double)v, INV_PI_D, 0.5));
    return (int)(((n1 + n2) & 1LL) ^ 1LL);   // 1 -> +1, 0 -> -1
}

// ---------------- K0: build Bmat [192][10240] bf16 ----------------
__global__ __launch_bounds__(256) void k0_build_B(
        const float* __restrict__ M, const float* __restrict__ cluster,
        ushort* __restrict__ Bmat) {
    int k = blockIdx.x * 256 + threadIdx.x;   // 0..10239
    int row = blockIdx.y;                      // 0..191
    ushort u = 0;
    if (k < DD) {
        if (row < 64) {
            u = f2bf(cluster[row * DD + k]);
        } else {
            float m = M[(row & 63) * DD + k];
            ushort mh = f2bf(m);
            if (row < 128) {
                u = mh;
            } else {
                float mhf = __builtin_bit_cast(float, (unsigned)mh << 16);
                u = f2bf(m - mhf);
            }
        }
    }
    Bmat[row * DPAD + k] = u;
}

// ---------------- K1: encode -> enc (+-1 f32), T_G ordering ----------------
// Reference dot identified by rounds 8-10 probes: 4 accumulators strided
// k mod 4 (SSE-width), FMA, pairwise-tree hsum (g0+g1)+(g2+g3).
// Signs of sinf(t)/cosf(t+b) via exact f64 floor parity at the f32 args.
__global__ __launch_bounds__(256) void k1_enc(
        const float* __restrict__ x, const float* __restrict__ W,
        const float* __restrict__ bias, float* __restrict__ enc_out) {
    __shared__ float xs[64 * SZ];
    const int tid = threadIdx.x;
    const int i0 = blockIdx.y * 64;
    const int k = blockIdx.x * 256 + tid;
    const bool valid = (k < DD);

    {
        const float4* xg = reinterpret_cast<const float4*>(x + (size_t)i0 * SZ);
        float4* xs4 = reinterpret_cast<float4*>(xs);
        xs4[tid] = xg[tid];
        xs4[tid + 256] = xg[tid + 256];
    }
    const int kw = valid ? k : 0;
    float4 w4[8];
    {
        const float4* wg = reinterpret_cast<const float4*>(W) + (size_t)kw * 8;
        #pragma unroll
        for (int c = 0; c < 8; ++c) w4[c] = wg[c];
    }
    const float bk = bias[kw];
    __syncthreads();

    for (int i = 0; i < 64; ++i) {
        const float4* xr = reinterpret_cast<const float4*>(xs + i * SZ);
        float g0 = 0.f, g1 = 0.f, g2 = 0.f, g3 = 0.f;
        #pragma unroll
        for (int c = 0; c < 8; ++c) {
            float4 xc = xr[c];   // LDS broadcast (uniform address)
            g0 = fmaf(w4[c].x, xc.x, g0);
            g1 = fmaf(w4[c].y, xc.y, g1);
            g2 = fmaf(w4[c].z, xc.z, g2);
            g3 = fmaf(w4[c].w, xc.w, g3);
        }
        float t = (g0 + g1) + (g2 + g3);
        int e = sign_pm(t, bk);
        if (valid) enc_out[(size_t)(i0 + i) * DD + k] = e ? 1.f : -1.f;
    }
}

// ---------------- K2: C[seg] = enc @ Bmat^T (bf16 MFMA) ----------------
// Stages A by SIGN of enc -> robust and exact (enc is +-1).
__global__ __launch_bounds__(256) void k2_gemm(
        const float* __restrict__ enc, const ushort* __restrict__ Bmat,
        float* __restrict__ Cpart) {
    __shared__ ushort As[64 * 72];
    __shared__ ushort Bs[NROWS_B * 72];

    const int tid = threadIdx.x;
    const int row0 = blockIdx.x * 64;
    const int seg = blockIdx.y;
    const int kbase = seg * KSEG;

    const int lane = tid & 63;
    const int wid = tid >> 6;
    const int wrow = (wid & 1) * 32;
    const int wcol = (wid >> 1) * 96;
    const int fr = lane & 15;
    const int fg = lane >> 4;

    const int arow = tid >> 2;          // 0..63
    const int aq = (tid & 3) * 16;      // k-offset 0/16/32/48

    f32x4 acc[2][6] = {};

    for (int step = 0; step < KSEG / 64; ++step) {
        const int kk0 = kbase + step * 64;
        __syncthreads();
        {
            ushort tmp[16];
            if (kk0 + 64 <= DD) {
                const float4* s4 = reinterpret_cast<const float4*>(
                    enc + (size_t)(row0 + arow) * DD + kk0 + aq);
                #pragma unroll
                for (int c = 0; c < 4; ++c) {
                    float4 f = s4[c];
                    tmp[c * 4 + 0] = (f.x > 0.f) ? 0x3F80 : 0xBF80;
                    tmp[c * 4 + 1] = (f.y > 0.f) ? 0x3F80 : 0xBF80;
                    tmp[c * 4 + 2] = (f.z > 0.f) ? 0x3F80 : 0xBF80;
                    tmp[c * 4 + 3] = (f.w > 0.f) ? 0x3F80 : 0xBF80;
                }
            } else {
                #pragma unroll
                for (int e = 0; e < 16; ++e) {
                    int kg = kk0 + aq + e;
                    ushort u = 0;
                    if (kg < DD) {
                        float f = enc[(size_t)(row0 + arow) * DD + kg];
                        u = (f > 0.f) ? 0x3F80 : 0xBF80;
                    }
                    tmp[e] = u;
                }
            }
            *reinterpret_cast<us8*>(&As[arow * 72 + aq]) = *reinterpret_cast<us8*>(&tmp[0]);
            *reinterpret_cast<us8*>(&As[arow * 72 + aq + 8]) = *reinterpret_cast<us8*>(&tmp[8]);
        }
        #pragma unroll
        for (int s = 0; s < 6; ++s) {
            int task = s * 256 + tid;       // 0..1535
            int brow = task >> 3;           // 0..191
            int bch = (task & 7) * 8;       // bf16 offset within 64
            uint4 vv = *reinterpret_cast<const uint4*>(Bmat + (size_t)brow * DPAD + kk0 + bch);
            *reinterpret_cast<uint4*>(&Bs[brow * 72 + bch]) = vv;
        }
        __syncthreads();
        #pragma unroll
        for (int h = 0; h < 2; ++h) {
            short8 a0 = *reinterpret_cast<const short8*>(&As[(wrow + 0 + fr) * 72 + h * 32 + fg * 8]);
            short8 a1 = *reinterpret_cast<const short8*>(&As[(wrow + 16 + fr) * 72 + h * 32 + fg * 8]);
            #pragma unroll
            for (int n = 0; n < 6; ++n) {
                short8 bb = *reinterpret_cast<const short8*>(&Bs[(wcol + n * 16 + fr) * 72 + h * 32 + fg * 8]);
                acc[0][n] = __builtin_amdgcn_mfma_f32_16x16x32_bf16(a0, bb, acc[0][n], 0, 0, 0);
                acc[1][n] = __builtin_amdgcn_mfma_f32_16x16x32_bf16(a1, bb, acc[1][n], 0, 0, 0);
            }
        }
    }

    #pragma unroll
    for (int m = 0; m < 2; ++m)
        #pragma unroll
        for (int n = 0; n < 6; ++n)
            #pragma unroll
            for (int r = 0; r < 4; ++r) {
                int grow = row0 + wrow + m * 16 + fg * 4 + r;
                int col = wcol + n * 16 + fr;
                Cpart[((size_t)seg * BB + grow) * NROWS_B + col] = acc[m][n][r];
            }
}

// ---------------- K3: reduce partials + softmax + combine ----------------
__global__ __launch_bounds__(256) void k3_final(
        const float* __restrict__ Cpart, float* __restrict__ res) {
    const int wid = threadIdx.x >> 6;
    const int lane = threadIdx.x & 63;
    const int row = blockIdx.x * 4 + wid;

    float s = 0.f, mh = 0.f, ml = 0.f;
    #pragma unroll
    for (int seg = 0; seg < KSPLIT; ++seg) {
        const float* base = Cpart + ((size_t)seg * BB + row) * NROWS_B;
        s += base[lane];
        mh += base[64 + lane];
        ml += base[128 + lane];
    }
    float sim = s * 1e-4f;          // exact norms: 100 * 100
    float mr = mh + ml;

    float mx = sim;
    #pragma unroll
    for (int o = 32; o; o >>= 1) mx = fmaxf(mx, __shfl_xor(mx, o, 64));
    float e = expf(sim - mx);
    float num = e * mr;
    float Z = e;
    #pragma unroll
    for (int o = 32; o; o >>= 1) {
        Z += __shfl_xor(Z, o, 64);
        num += __shfl_xor(num, o, 64);
    }
    if (lane == 0) res[row] = num / Z;
}

extern "C" void kernel_launch(void* const* d_in, const int* in_sizes, int n_in,
                              void* d_out, int out_size, void* d_ws, size_t ws_size,
                              hipStream_t stream) {
    const float* x = (const float*)d_in[0];
    const float* W = (const float*)d_in[1];
    const float* bias = (const float*)d_in[2];
    const float* M = (const float*)d_in[3];
    const float* cluster = (const float*)d_in[4];

    float* res = (float*)d_out;            // [4096]
    float* enc = (float*)d_out + BB;       // [4096][10000]

    ushort* Bmat = (ushort*)d_ws;                            // 3.93 MB
    float* Cpart = (float*)((char*)d_ws + ((size_t)4 << 20)); // 12.6 MB

    k0_build_B<<<dim3(40, 192), 256, 0, stream>>>(M, cluster, Bmat);
    k1_enc<<<dim3(40, 64), 256, 0, stream>>>(x, W, bias, enc);
    k2_gemm<<<dim3(64, KSPLIT), 256, 0, stream>>>(enc, Bmat, Cpart);
    k3_final<<<BB / 4, 256, 0, stream>>>(Cpart, res);
}